// Round 8
// baseline (487.945 us; speedup 1.0000x reference)
//
#include <hip/hip_runtime.h>
#include <hip/hip_cooperative_groups.h>
#include <hip/hip_bf16.h>
#include <math.h>

#define DIM 1024
#define HID 2048
#define NE  4
#define NT  4096            // B*T tokens
#define KW  (NE*HID)        // 8192, GEMM2 K / Hw leading dim
#define KSPLIT 2
#define KCH (KW / KSPLIT)   // 4096 per split

namespace cg = cooperative_groups;

typedef __attribute__((ext_vector_type(8))) short short8;
typedef __attribute__((ext_vector_type(4))) short short4v;
typedef __attribute__((ext_vector_type(4))) float floatx4;

// ---- helpers ----------------------------------------------------------------

__device__ __forceinline__ void async_cp16(const void* g, void* l) {
  __builtin_amdgcn_global_load_lds(
      (const __attribute__((address_space(1))) void*)g,
      (__attribute__((address_space(3))) void*)l, 16, 0, 0);
}

__device__ __forceinline__ short f2bf(float f) {
  union { float f; unsigned u; } x; x.f = f;
  unsigned r = x.u + 0x7fffu + ((x.u >> 16) & 1u);   // round-to-nearest-even
  return (short)(r >> 16);
}

// fast GELU (tanh form via sigmoid + v_exp/v_rcp); |err| ~2e-4 vs exact
__device__ __forceinline__ float gelu_fast(float v) {
  float u = 1.595769122f * (v + 0.044715f * v * v * v);
  return v * __builtin_amdgcn_rcpf(1.0f + __expf(-u));
}

#define TP_PADR 136   // transpose LDS row stride (shorts); 272B, 16B-aligned

// ============================================================================
// ONE persistent cooperative kernel, 512 blocks (2/CU co-resident), 4 phases
// separated by grid.sync(). Phase bodies are the R6-benched kernels verbatim:
//   GEMMs: 128x128 tile, BK=64, both operands via LDS (R7's direct-global B
//   regressed 284->420us: 16 scattered 64B segments/load, latency-exposed),
//   XOR k-slot swizzle (0 bank conflicts), XCD bricks via bid&7 (R6: FETCH
//   271->66MB), split-K=2 + streaming reduce (atomicAdd regressed, R4).
// Rationale: R6 kernel-time sum ~200us vs 284us wall -> ~70us of serialized
// inter-kernel gaps; grid.sync() replaces 3 full drain+launch boundaries.
// ============================================================================
__global__ void __launch_bounds__(256, 2)
moe_fused(const float* __restrict__ x,  const float* __restrict__ Wr,
          const float* __restrict__ br,
          const float* __restrict__ W1, const float* __restrict__ b1,
          const float* __restrict__ W2, const float* __restrict__ b2,
          float* __restrict__ wgt, short* __restrict__ xb,
          short* __restrict__ w1t, short* __restrict__ w2t,
          short* __restrict__ hw,  float* __restrict__ part,
          float* __restrict__ out)
{
  cg::grid_group gg = cg::this_grid();
  const int rb  = blockIdx.x;          // 0..511
  const int tid = threadIdx.x;

  __shared__ __align__(16) short As[128 * 64];
  __shared__ __align__(16) short Bs[128 * 64];

  // common GEMM lane decode
  const int lane = tid & 63;
  const int wv   = tid >> 6;
  const int wm   = (wv >> 1) * 64, wn = (wv & 1) * 64;
  const int quad = lane >> 4, lrow = lane & 15;
  const int sr   = tid >> 3;                       // staging row-in-call 0..31
  const int kof  = ((tid & 7) ^ (sr & 7)) * 8;     // swizzled global k offset
  const int rkey = lrow & 7;                       // read-side swizzle key

  // ---------------- P0: prep (router+cvt 1024 vb, transposes 4096 vb) -------
  for (int vb = rb; vb < 5120; vb += 512) {
    if (vb < 1024) {
      const int t = vb * 4 + wv;
      const float* xr = x + (size_t)t * DIM;
      short* xo = xb + (size_t)t * DIM;
      float a0 = 0.f, a1 = 0.f, a2 = 0.f, a3 = 0.f;
      #pragma unroll
      for (int p = 0; p < 4; p++) {
        const int d = p * 256 + lane * 4;
        floatx4 v = *(const floatx4*)&xr[d];
        short4v o;
        #pragma unroll
        for (int j = 0; j < 4; j++) {
          o[j] = f2bf(v[j]);
          floatx4 wr = *(const floatx4*)&Wr[(d + j) * 4];
          a0 += v[j] * wr[0]; a1 += v[j] * wr[1];
          a2 += v[j] * wr[2]; a3 += v[j] * wr[3];
        }
        *(short4v*)&xo[d] = o;
      }
      #pragma unroll
      for (int off = 32; off; off >>= 1) {
        a0 += __shfl_down(a0, off);
        a1 += __shfl_down(a1, off);
        a2 += __shfl_down(a2, off);
        a3 += __shfl_down(a3, off);
      }
      a0 = __shfl(a0, 0); a1 = __shfl(a1, 0); a2 = __shfl(a2, 0); a3 = __shfl(a3, 0);
      float s0 = a0 + br[0], s1 = a1 + br[1], s2 = a2 + br[2], s3 = a3 + br[3];
      float m = fmaxf(fmaxf(s0, s1), fmaxf(s2, s3));
      float e0 = __expf(s0 - m), e1 = __expf(s1 - m);
      float e2 = __expf(s2 - m), e3 = __expf(s3 - m);
      float inv = 1.f / (e0 + e1 + e2 + e3);
      float v = (lane == 0) ? e0 : (lane == 1) ? e1 : (lane == 2) ? e2 : e3;
      if (lane < 4) wgt[t * 4 + lane] = v * inv;
    } else {
      // transpose fp32 [z][R][C] -> bf16 [z][C][R], tile 128r x 32c, via As
      short* tile = As;
      const int b = vb - 1024;
      const float* in; short* o; int R, C, xt, yt;
      if (b < 2048) {               // W1: per expert R=DIM rows, C=HID cols
        const int e = b >> 9, rem = b & 511;
        xt = rem & 63; yt = rem >> 6; R = DIM; C = HID;
        in = W1 + (size_t)e * DIM * HID; o = w1t + (size_t)e * DIM * HID;
      } else {                      // W2: R=KW rows, C=DIM cols
        const int rem = b - 2048;
        xt = rem & 31; yt = rem >> 5; R = KW; C = DIM;
        in = W2; o = w2t;
      }
      const int c0 = xt * 32, r0 = yt * 128;
      const int cin = (tid & 7) * 4;
      const int rin = tid >> 3;               // 0..31
      #pragma unroll
      for (int i = 0; i < 4; i++) {
        const int r = rin + i * 32;
        floatx4 v = *(const floatx4*)&in[(size_t)(r0 + r) * C + c0 + cin];
        #pragma unroll
        for (int j = 0; j < 4; j++)
          tile[(cin + j) * TP_PADR + r] = f2bf(v[j]);
      }
      __syncthreads();
      const int ct = tid >> 3;                // 0..31
      #pragma unroll
      for (int i = 0; i < 2; i++) {
        const int rc = (tid & 7) + 8 * i;     // 8-short chunks
        short8 vv = *(const short8*)&tile[ct * TP_PADR + rc * 8];
        *(short8*)&o[(size_t)(c0 + ct) * R + r0 + rc * 8] = vv;
      }
    }
    __syncthreads();
  }
  gg.sync();

  // ---------------- P1: gemm1 — Hw = bf16(w * gelu(x@W1+b1)) ----------------
  // 2048 vb; XCD brick {8m x 16n x 2e} (vb&7 == rb&7 across iterations)
  for (int vb = rb; vb < 2048; vb += 512) {
    const int xcd = vb & 7, slot = vb >> 3;
    const int m_grp = xcd & 3;
    const int n_idx = slot & 15, m_off = (slot >> 4) & 7, e_off = slot >> 7;
    const int e  = (xcd >> 2) * 2 + e_off;
    const int m0 = (m_grp * 8 + m_off) * 128;
    const int n0 = n_idx * 128;

    const short* Ap = xb;
    const short* Bp = w1t + (size_t)e * HID * DIM;

    floatx4 acc[4][4];
    #pragma unroll
    for (int i = 0; i < 4; i++)
      #pragma unroll
      for (int j = 0; j < 4; j++) acc[i][j] = (floatx4)0.f;

    for (int k0 = 0; k0 < DIM; k0 += 64) {
      __syncthreads();
      #pragma unroll
      for (int c = 0; c < 4; c++)
        async_cp16(Ap + (size_t)(m0 + c * 32 + sr) * DIM + k0 + kof,
                   As + (c * 256 + tid) * 8);
      #pragma unroll
      for (int c = 0; c < 4; c++)
        async_cp16(Bp + (size_t)(n0 + c * 32 + sr) * DIM + k0 + kof,
                   Bs + (c * 256 + tid) * 8);
      __syncthreads();
      #pragma unroll
      for (int kk = 0; kk < 2; kk++) {
        short8 af[4], bf[4];
        const int ko = ((kk * 4 + quad) ^ rkey) * 8;
        #pragma unroll
        for (int i = 0; i < 4; i++)
          af[i] = *(const short8*)&As[(wm + i * 16 + lrow) * 64 + ko];
        #pragma unroll
        for (int j = 0; j < 4; j++)
          bf[j] = *(const short8*)&Bs[(wn + j * 16 + lrow) * 64 + ko];
        #pragma unroll
        for (int i = 0; i < 4; i++)
          #pragma unroll
          for (int j = 0; j < 4; j++)
            acc[i][j] = __builtin_amdgcn_mfma_f32_16x16x32_bf16(af[i], bf[j], acc[i][j], 0, 0, 0);
      }
    }

    #pragma unroll
    for (int i = 0; i < 4; i++) {
      const int rbase = m0 + wm + i * 16 + quad * 4;
      float wv4[4];
      #pragma unroll
      for (int r = 0; r < 4; r++) wv4[r] = wgt[(rbase + r) * NE + e];
      #pragma unroll
      for (int j = 0; j < 4; j++) {
        const int col = n0 + wn + j * 16 + lrow;          // h
        const float b1v = b1[e * HID + col];
        #pragma unroll
        for (int r = 0; r < 4; r++) {
          float v = acc[i][j][r] + b1v;
          hw[(size_t)(rbase + r) * KW + e * HID + col] = f2bf(wv4[r] * gelu_fast(v));
        }
      }
    }
  }
  gg.sync();

  // ---------------- P2: gemm2 (split-K=2) — out / part ----------------------
  // 512 vb (= rb); XCD brick {8m x 8n x 1kz}
  {
    const int xcd = rb & 7, slot = rb >> 3;
    const int m_grp = xcd & 3, kz = xcd >> 2;
    const int n_idx = slot & 7, m_off = slot >> 3;
    const int m0 = (m_grp * 8 + m_off) * 128;
    const int n0 = n_idx * 128;

    floatx4 acc[4][4];
    #pragma unroll
    for (int i = 0; i < 4; i++)
      #pragma unroll
      for (int j = 0; j < 4; j++) acc[i][j] = (floatx4)0.f;

    const int kbeg = kz * KCH;
    for (int kk0 = 0; kk0 < KCH; kk0 += 64) {
      const int k0 = kbeg + kk0;
      __syncthreads();
      #pragma unroll
      for (int c = 0; c < 4; c++)
        async_cp16(hw + (size_t)(m0 + c * 32 + sr) * KW + k0 + kof,
                   As + (c * 256 + tid) * 8);
      #pragma unroll
      for (int c = 0; c < 4; c++)
        async_cp16(w2t + (size_t)(n0 + c * 32 + sr) * KW + k0 + kof,
                   Bs + (c * 256 + tid) * 8);
      __syncthreads();
      #pragma unroll
      for (int kk = 0; kk < 2; kk++) {
        short8 af[4], bf[4];
        const int ko = ((kk * 4 + quad) ^ rkey) * 8;
        #pragma unroll
        for (int i = 0; i < 4; i++)
          af[i] = *(const short8*)&As[(wm + i * 16 + lrow) * 64 + ko];
        #pragma unroll
        for (int j = 0; j < 4; j++)
          bf[j] = *(const short8*)&Bs[(wn + j * 16 + lrow) * 64 + ko];
        #pragma unroll
        for (int i = 0; i < 4; i++)
          #pragma unroll
          for (int j = 0; j < 4; j++)
            acc[i][j] = __builtin_amdgcn_mfma_f32_16x16x32_bf16(af[i], bf[j], acc[i][j], 0, 0, 0);
      }
    }

    if (kz == 0) {
      #pragma unroll
      for (int i = 0; i < 4; i++) {
        const int rbase = m0 + wm + i * 16 + quad * 4;
        floatx4 wr[4];
        #pragma unroll
        for (int r = 0; r < 4; r++) wr[r] = *(const floatx4*)&wgt[(rbase + r) * NE];
        #pragma unroll
        for (int j = 0; j < 4; j++) {
          const int col = n0 + wn + j * 16 + lrow;
          float b2v[4];
          #pragma unroll
          for (int eI = 0; eI < 4; eI++) b2v[eI] = b2[eI * DIM + col];
          #pragma unroll
          for (int r = 0; r < 4; r++) {
            float bias = wr[r][0] * b2v[0] + wr[r][1] * b2v[1] +
                         wr[r][2] * b2v[2] + wr[r][3] * b2v[3];
            out[(size_t)(rbase + r) * DIM + col] = acc[i][j][r] + bias;
          }
        }
      }
    } else {
      #pragma unroll
      for (int i = 0; i < 4; i++) {
        const int rbase = m0 + wm + i * 16 + quad * 4;
        #pragma unroll
        for (int j = 0; j < 4; j++) {
          const int col = n0 + wn + j * 16 + lrow;
          #pragma unroll
          for (int r = 0; r < 4; r++)
            part[(size_t)(rbase + r) * DIM + col] = acc[i][j][r];
        }
      }
    }
  }
  gg.sync();

  // ---------------- P3: reduce — out += part --------------------------------
  for (int i = (rb * 256 + tid) * 4; i < NT * DIM; i += 512 * 256 * 4) {
    floatx4 v = *(const floatx4*)&out[i];
    floatx4 a = *(const floatx4*)&part[i];
    v = v + a;
    *(floatx4*)&out[i] = v;
  }
}

// ---- launch -----------------------------------------------------------------

extern "C" void kernel_launch(void* const* d_in, const int* in_sizes, int n_in,
                              void* d_out, int out_size, void* d_ws, size_t ws_size,
                              hipStream_t stream) {
  const float* x  = (const float*)d_in[0];
  const float* W1 = (const float*)d_in[1];
  const float* b1 = (const float*)d_in[2];
  const float* W2 = (const float*)d_in[3];
  const float* b2 = (const float*)d_in[4];
  const float* Wr = (const float*)d_in[5];
  const float* br = (const float*)d_in[6];
  float* out = (float*)d_out;

  // layout (bytes):
  //   wgt  @ 0        64 KB   fp32 [NT][NE]
  //   w2t  @ 64K      16 MB   bf16 [DIM][KW]
  //   hw   @ ~16.1M   64 MB   bf16 [NT][KW]
  //   xb   @ ~80.1M    8 MB   bf16 [NT][DIM]     (dead after gemm1)
  //   w1t  @ ~88.5M   16 MB   bf16 [NE][HID][DIM](dead after gemm1)
  //   part @ ~80.1M   16 MB   fp32 [NT][DIM]     (aliases xb+w1t head)
  char* ws = (char*)d_ws;
  float* wgt = (float*)(ws);
  short* w2t = (short*)(ws + 65536);
  short* hw  = (short*)(ws + 65536 + 16777216);
  short* xb  = (short*)(ws + 65536 + 16777216 + 67108864);
  short* w1t = (short*)(ws + 65536 + 16777216 + 67108864 + 8388608);
  float* part= (float*)(ws + 65536 + 16777216 + 67108864);   // aliases xb/w1t

  void* args[] = {
    (void*)&x, (void*)&Wr, (void*)&br, (void*)&W1, (void*)&b1,
    (void*)&W2, (void*)&b2, (void*)&wgt, (void*)&xb, (void*)&w1t,
    (void*)&w2t, (void*)&hw, (void*)&part, (void*)&out
  };
  hipLaunchCooperativeKernel((void*)moe_fused, dim3(512), dim3(256),
                             args, 0, stream);
}

// Round 9
// 380.175 us; speedup vs baseline: 1.2835x; 1.2835x over previous
//
#include <hip/hip_runtime.h>
#include <hip/hip_bf16.h>
#include <math.h>

#define DIM 1024
#define HID 2048
#define NE  4
#define NT  4096            // B*T tokens
#define KW  (NE*HID)        // 8192, GEMM2 K / Hw leading dim
#define KSPLIT 2
#define KCH (KW / KSPLIT)   // 4096 per split
#define FLAG_MAGIC 0x13579BDF

typedef __attribute__((ext_vector_type(8))) short short8;
typedef __attribute__((ext_vector_type(4))) short short4v;
typedef __attribute__((ext_vector_type(4))) float floatx4;

// ---- helpers ----------------------------------------------------------------

__device__ __forceinline__ void async_cp16(const void* g, void* l) {
  __builtin_amdgcn_global_load_lds(
      (const __attribute__((address_space(1))) void*)g,
      (__attribute__((address_space(3))) void*)l, 16, 0, 0);
}

__device__ __forceinline__ short f2bf(float f) {
  union { float f; unsigned u; } x; x.f = f;
  unsigned r = x.u + 0x7fffu + ((x.u >> 16) & 1u);   // round-to-nearest-even
  return (short)(r >> 16);
}

// fast GELU (tanh form via sigmoid + v_exp/v_rcp); |err| ~2e-4 vs exact
__device__ __forceinline__ float gelu_fast(float v) {
  float u = 1.595769122f * (v + 0.044715f * v * v * v);
  return v * __builtin_amdgcn_rcpf(1.0f + __expf(-u));
}

// ---- fused prep: router softmax + x->bf16 (1024 vb) + weight transposes -----
#define TP_PADR 136   // LDS row stride (shorts); 272B, 16B-aligned
__global__ void prep_kernel(const float* __restrict__ x, const float* __restrict__ Wr,
                            const float* __restrict__ br, float* __restrict__ wgt,
                            short* __restrict__ xb,
                            const float* __restrict__ W1, short* __restrict__ w1t,
                            const float* __restrict__ W2, short* __restrict__ w2t) {
  __shared__ __align__(16) short tile[32 * TP_PADR];
  const int bb = blockIdx.x;
  const int tid = threadIdx.x;
  if (bb < 1024) {
    const int wv = tid >> 6, lane = tid & 63;
    const int t = bb * 4 + wv;
    const float* xr = x + (size_t)t * DIM;
    short* xo = xb + (size_t)t * DIM;
    float a0 = 0.f, a1 = 0.f, a2 = 0.f, a3 = 0.f;
    #pragma unroll
    for (int p = 0; p < 4; p++) {
      const int d = p * 256 + lane * 4;
      floatx4 v = *(const floatx4*)&xr[d];
      short4v o;
      #pragma unroll
      for (int j = 0; j < 4; j++) {
        o[j] = f2bf(v[j]);
        floatx4 wr = *(const floatx4*)&Wr[(d + j) * 4];
        a0 += v[j] * wr[0]; a1 += v[j] * wr[1];
        a2 += v[j] * wr[2]; a3 += v[j] * wr[3];
      }
      *(short4v*)&xo[d] = o;
    }
    #pragma unroll
    for (int off = 32; off; off >>= 1) {
      a0 += __shfl_down(a0, off);
      a1 += __shfl_down(a1, off);
      a2 += __shfl_down(a2, off);
      a3 += __shfl_down(a3, off);
    }
    a0 = __shfl(a0, 0); a1 = __shfl(a1, 0); a2 = __shfl(a2, 0); a3 = __shfl(a3, 0);
    float s0 = a0 + br[0], s1 = a1 + br[1], s2 = a2 + br[2], s3 = a3 + br[3];
    float m = fmaxf(fmaxf(s0, s1), fmaxf(s2, s3));
    float e0 = __expf(s0 - m), e1 = __expf(s1 - m);
    float e2 = __expf(s2 - m), e3 = __expf(s3 - m);
    float inv = 1.f / (e0 + e1 + e2 + e3);
    float v = (lane == 0) ? e0 : (lane == 1) ? e1 : (lane == 2) ? e2 : e3;
    if (lane < 4) wgt[t * 4 + lane] = v * inv;
    return;
  }
  // weight transpose: fp32 [z][R][C] -> bf16 [z][C][R], tile 128r x 32c
  const int b = bb - 1024;
  const float* in; short* o; int R, C, xt, yt;
  if (b < 2048) {                 // W1: per expert R=DIM rows, C=HID cols
    const int e = b >> 9, rem = b & 511;
    xt = rem & 63; yt = rem >> 6; R = DIM; C = HID;
    in = W1 + (size_t)e * DIM * HID; o = w1t + (size_t)e * DIM * HID;
  } else {                        // W2: R=KW rows, C=DIM cols
    const int rem = b - 2048;
    xt = rem & 31; yt = rem >> 5; R = KW; C = DIM;
    in = W2; o = w2t;
  }
  const int c0 = xt * 32, r0 = yt * 128;
  const int cin = (tid & 7) * 4;
  const int rin = tid >> 3;                 // 0..31
  #pragma unroll
  for (int i = 0; i < 4; i++) {
    const int r = rin + i * 32;
    floatx4 v = *(const floatx4*)&in[(size_t)(r0 + r) * C + c0 + cin];
    #pragma unroll
    for (int j = 0; j < 4; j++)
      tile[(cin + j) * TP_PADR + r] = f2bf(v[j]);
  }
  __syncthreads();
  const int ct = tid >> 3;                  // 0..31
  #pragma unroll
  for (int i = 0; i < 2; i++) {
    const int rc = (tid & 7) + 8 * i;       // 8-short chunks
    short8 vv = *(const short8*)&tile[ct * TP_PADR + rc * 8];
    *(short8*)&o[(size_t)(c0 + ct) * R + r0 + rc * 8] = vv;
  }
}

// ============================================================================
// GEMM tiles: 128x128, BK=64 (LDS 2x16KB), bf16 16x16x32 MFMA, 4 waves.
// Both operands via LDS (R7 direct-global B regressed: scattered 64B segments).
// XOR k-slot swizzle: 0 bank conflicts (R3). XCD bricks via bid&7 (R6:
// FETCH 271->66MB). Separate dispatches, NOT a persistent megakernel (R8:
// lock-stepped phases regressed 284->488). Split-K=2; partner combine via
// device-scope flag replaces the reduce kernel (atomicAdd combine itself
// regressed in R4 -- flags serialize only 1 dword/tile, not 16M RMWs).
// ============================================================================

// ---- GEMM1: Hw[t][e*HID+h] = bf16( w[t][e] * gelu(x @ W1[e] + b1[e]) ) ------
// grid 2048: XCD brick {8m x 16n x 2e} (A shared across e)
__global__ __launch_bounds__(256, 2)
void gemm1_kernel(const short* __restrict__ xb, const short* __restrict__ w1t,
                  const float* __restrict__ b1, const float* __restrict__ wgt,
                  short* __restrict__ hw) {
  const int b = blockIdx.x;
  const int xcd = b & 7, slot = b >> 3;            // slot 0..255
  const int m_grp = xcd & 3;
  const int n_idx = slot & 15, m_off = (slot >> 4) & 7, e_off = slot >> 7;
  const int e  = (xcd >> 2) * 2 + e_off;
  const int m0 = (m_grp * 8 + m_off) * 128;
  const int n0 = n_idx * 128;
  const int tid = threadIdx.x;
  const int lane = tid & 63;
  const int wv = tid >> 6;
  const int wm = (wv >> 1) * 64, wn = (wv & 1) * 64;
  const int quad = lane >> 4, lrow = lane & 15;
  const int sr  = tid >> 3;                        // staging row-in-call 0..31
  const int kof = ((tid & 7) ^ (sr & 7)) * 8;      // swizzled global k offset
  const int rkey = lrow & 7;                       // read-side swizzle key

  __shared__ __align__(16) short As[128 * 64];
  __shared__ __align__(16) short Bs[128 * 64];

  const short* Ap = xb;
  const short* Bp = w1t + (size_t)e * HID * DIM;

  floatx4 acc[4][4];
  #pragma unroll
  for (int i = 0; i < 4; i++)
    #pragma unroll
    for (int j = 0; j < 4; j++) acc[i][j] = (floatx4)0.f;

  for (int k0 = 0; k0 < DIM; k0 += 64) {
    __syncthreads();
    #pragma unroll
    for (int c = 0; c < 4; c++)
      async_cp16(Ap + (size_t)(m0 + c * 32 + sr) * DIM + k0 + kof,
                 As + (c * 256 + tid) * 8);
    #pragma unroll
    for (int c = 0; c < 4; c++)
      async_cp16(Bp + (size_t)(n0 + c * 32 + sr) * DIM + k0 + kof,
                 Bs + (c * 256 + tid) * 8);
    __syncthreads();
    #pragma unroll
    for (int kk = 0; kk < 2; kk++) {
      short8 af[4], bf[4];
      const int ko = ((kk * 4 + quad) ^ rkey) * 8;
      #pragma unroll
      for (int i = 0; i < 4; i++)
        af[i] = *(const short8*)&As[(wm + i * 16 + lrow) * 64 + ko];
      #pragma unroll
      for (int j = 0; j < 4; j++)
        bf[j] = *(const short8*)&Bs[(wn + j * 16 + lrow) * 64 + ko];
      #pragma unroll
      for (int i = 0; i < 4; i++)
        #pragma unroll
        for (int j = 0; j < 4; j++)
          acc[i][j] = __builtin_amdgcn_mfma_f32_16x16x32_bf16(af[i], bf[j], acc[i][j], 0, 0, 0);
    }
  }

  #pragma unroll
  for (int i = 0; i < 4; i++) {
    const int rbase = m0 + wm + i * 16 + quad * 4;
    float wv4[4];
    #pragma unroll
    for (int r = 0; r < 4; r++) wv4[r] = wgt[(rbase + r) * NE + e];
    #pragma unroll
    for (int j = 0; j < 4; j++) {
      const int col = n0 + wn + j * 16 + lrow;          // h
      const float b1v = b1[e * HID + col];
      #pragma unroll
      for (int r = 0; r < 4; r++) {
        float v = acc[i][j][r] + b1v;
        hw[(size_t)(rbase + r) * KW + e * HID + col] = f2bf(wv4[r] * gelu_fast(v));
      }
    }
  }
}

// ---- GEMM2 (split-K=2, flag pair-combine): out = Hw@W2t^T + weighted bias ---
// grid 512: XCD brick {8m x 8n x 1kz}. kz==1 stores fp32 partial + release
// flag; kz==0 spin-acquires partner flag, writes out = acc + part + bias.
// Deadlock-free: writers never wait; 512 blocks are all co-resident anyway.
// Poison-safe: flags start 0xAAAAAAAA (harness re-poison) != FLAG_MAGIC.
__global__ __launch_bounds__(256, 2)
void gemm2_kernel(const short* __restrict__ hw, const short* __restrict__ w2t,
                  const float* __restrict__ b2, const float* __restrict__ wgt,
                  float* __restrict__ out, float* __restrict__ part,
                  int* __restrict__ flags) {
  const int b = blockIdx.x;
  const int xcd = b & 7, slot = b >> 3;            // slot 0..63
  const int m_grp = xcd & 3, kz = xcd >> 2;
  const int n_idx = slot & 7, m_off = slot >> 3;
  const int m0 = (m_grp * 8 + m_off) * 128;
  const int n0 = n_idx * 128;
  const int pid = (m_grp * 8 + m_off) * 8 + n_idx; // tile-pair id 0..255
  const int tid = threadIdx.x;
  const int lane = tid & 63;
  const int wv = tid >> 6;
  const int wm = (wv >> 1) * 64, wn = (wv & 1) * 64;
  const int quad = lane >> 4, lrow = lane & 15;
  const int sr  = tid >> 3;
  const int kof = ((tid & 7) ^ (sr & 7)) * 8;
  const int rkey = lrow & 7;

  __shared__ __align__(16) short As[128 * 64];
  __shared__ __align__(16) short Bs[128 * 64];

  floatx4 acc[4][4];
  #pragma unroll
  for (int i = 0; i < 4; i++)
    #pragma unroll
    for (int j = 0; j < 4; j++) acc[i][j] = (floatx4)0.f;

  const int kbeg = kz * KCH;
  for (int kk0 = 0; kk0 < KCH; kk0 += 64) {
    const int k0 = kbeg + kk0;
    __syncthreads();
    #pragma unroll
    for (int c = 0; c < 4; c++)
      async_cp16(hw + (size_t)(m0 + c * 32 + sr) * KW + k0 + kof,
                 As + (c * 256 + tid) * 8);
    #pragma unroll
    for (int c = 0; c < 4; c++)
      async_cp16(w2t + (size_t)(n0 + c * 32 + sr) * KW + k0 + kof,
                 Bs + (c * 256 + tid) * 8);
    __syncthreads();
    #pragma unroll
    for (int kk = 0; kk < 2; kk++) {
      short8 af[4], bf[4];
      const int ko = ((kk * 4 + quad) ^ rkey) * 8;
      #pragma unroll
      for (int i = 0; i < 4; i++)
        af[i] = *(const short8*)&As[(wm + i * 16 + lrow) * 64 + ko];
      #pragma unroll
      for (int j = 0; j < 4; j++)
        bf[j] = *(const short8*)&Bs[(wn + j * 16 + lrow) * 64 + ko];
      #pragma unroll
      for (int i = 0; i < 4; i++)
        #pragma unroll
        for (int j = 0; j < 4; j++)
          acc[i][j] = __builtin_amdgcn_mfma_f32_16x16x32_bf16(af[i], bf[j], acc[i][j], 0, 0, 0);
    }
  }

  if (kz == 1) {
    #pragma unroll
    for (int i = 0; i < 4; i++) {
      const int rbase = m0 + wm + i * 16 + quad * 4;
      #pragma unroll
      for (int j = 0; j < 4; j++) {
        const int col = n0 + wn + j * 16 + lrow;
        #pragma unroll
        for (int r = 0; r < 4; r++)
          part[(size_t)(rbase + r) * DIM + col] = acc[i][j][r];
      }
    }
    __threadfence();          // publish partial (device scope)
    __syncthreads();          // all threads' stores fenced before flag
    if (tid == 0)
      __hip_atomic_store(&flags[pid], FLAG_MAGIC, __ATOMIC_RELEASE,
                         __HIP_MEMORY_SCOPE_AGENT);
  } else {
    // spin until partner's partial is published (every thread acquires ->
    // per-wave L1 invalidation on its own path)
    while (__hip_atomic_load(&flags[pid], __ATOMIC_ACQUIRE,
                             __HIP_MEMORY_SCOPE_AGENT) != FLAG_MAGIC)
      __builtin_amdgcn_s_sleep(2);
    #pragma unroll
    for (int i = 0; i < 4; i++) {
      const int rbase = m0 + wm + i * 16 + quad * 4;
      floatx4 wr[4];
      #pragma unroll
      for (int r = 0; r < 4; r++) wr[r] = *(const floatx4*)&wgt[(rbase + r) * NE];
      #pragma unroll
      for (int j = 0; j < 4; j++) {
        const int col = n0 + wn + j * 16 + lrow;
        float b2v[4];
        #pragma unroll
        for (int eI = 0; eI < 4; eI++) b2v[eI] = b2[eI * DIM + col];
        #pragma unroll
        for (int r = 0; r < 4; r++) {
          float bias = wr[r][0] * b2v[0] + wr[r][1] * b2v[1] +
                       wr[r][2] * b2v[2] + wr[r][3] * b2v[3];
          float p = part[(size_t)(rbase + r) * DIM + col];
          out[(size_t)(rbase + r) * DIM + col] = acc[i][j][r] + p + bias;
        }
      }
    }
  }
}

// ---- launch -----------------------------------------------------------------

extern "C" void kernel_launch(void* const* d_in, const int* in_sizes, int n_in,
                              void* d_out, int out_size, void* d_ws, size_t ws_size,
                              hipStream_t stream) {
  const float* x  = (const float*)d_in[0];
  const float* W1 = (const float*)d_in[1];
  const float* b1 = (const float*)d_in[2];
  const float* W2 = (const float*)d_in[3];
  const float* b2 = (const float*)d_in[4];
  const float* Wr = (const float*)d_in[5];
  const float* br = (const float*)d_in[6];
  float* out = (float*)d_out;

  // layout (bytes):
  //   wgt   @ 0        64 KB   fp32 [NT][NE]
  //   w2t   @ 64K      16 MB   bf16 [DIM][KW]
  //   hw    @ ~16.1M   64 MB   bf16 [NT][KW]
  //   xb    @ ~80.1M    8 MB   bf16 [NT][DIM]     (dead after gemm1)
  //   w1t   @ ~88.5M   16 MB   bf16 [NE][HID][DIM](dead after gemm1)
  //   part  @ ~80.1M   16 MB   fp32 [NT][DIM]     (aliases xb+w1t head)
  //   flags @ ~104.5M   1 KB   int  [256]         (fresh; poisoned 0xAA ok)
  char* ws = (char*)d_ws;
  float* wgt = (float*)(ws);
  short* w2t = (short*)(ws + 65536);
  short* hw  = (short*)(ws + 65536 + 16777216);
  short* xb  = (short*)(ws + 65536 + 16777216 + 67108864);
  short* w1t = (short*)(ws + 65536 + 16777216 + 67108864 + 8388608);
  float* part= (float*)(ws + 65536 + 16777216 + 67108864);   // aliases xb/w1t
  int* flags = (int*)(ws + 65536 + 16777216 + 67108864 + 8388608 + 16777216);

  hipLaunchKernelGGL(prep_kernel, dim3(1024 + 4096), dim3(256), 0, stream,
                     x, Wr, br, wgt, xb, W1, w1t, W2, w2t);
  hipLaunchKernelGGL(gemm1_kernel, dim3(2048), dim3(256), 0, stream,
                     xb, w1t, b1, wgt, hw);
  hipLaunchKernelGGL(gemm2_kernel, dim3(512), dim3(256), 0, stream,
                     hw, w2t, b2, wgt, out, part, flags);
}